// Round 4
// baseline (842.840 us; speedup 1.0000x reference)
//
#include <hip/hip_runtime.h>
#include <hip/hip_bf16.h>

#define NN0 200000
#define NN1 50000
#define NN2 10000
#define IN_DIM 512
#define HD 256
#define OUT_D 128

typedef unsigned short u16;
typedef unsigned int u32;
typedef __attribute__((ext_vector_type(8))) short s16x8;
typedef __attribute__((ext_vector_type(4))) float f32x4;

__device__ __forceinline__ float b2f(u16 u){ return __uint_as_float(((u32)u)<<16); }
__device__ __forceinline__ u16 f2b(float f){
  u32 x = __float_as_uint(f);
  u32 r = x + 0x7fffu + ((x>>16)&1u);
  return (u16)(r>>16);
}

// ---- degree counting (int atomics) ----
__global__ void deg_count(const int* __restrict__ src, const int* __restrict__ dst,
                          int E, int* __restrict__ outc, int* __restrict__ inc){
  int i = blockIdx.x*blockDim.x + threadIdx.x;
  if (i < E){
    atomicAdd(&outc[src[i]], 1);
    atomicAdd(&inc[dst[i]], 1);
  }
}

__global__ void mkscale(const int* __restrict__ c, float* __restrict__ o, int n){
  int i = blockIdx.x*blockDim.x + threadIdx.x;
  if (i < n) o[i] = rsqrtf((float)(c[i] > 1 ? c[i] : 1));
}

// ---- exclusive scan (single block, shuffle-based) ----
__global__ __launch_bounds__(1024) void scan_kernel(const int* __restrict__ cnt,
    int* __restrict__ off, int* __restrict__ cur, int n){
  __shared__ int wsum[16];
  int tid = threadIdx.x, lane = tid & 63, wv = tid >> 6;
  int carry = 0;
  for (int base = 0; base < n; base += 1024){
    int i = base + tid;
    int v = (i < n) ? cnt[i] : 0;
    int x = v;
    #pragma unroll
    for (int d = 1; d < 64; d <<= 1){
      int y = __shfl_up(x, d);
      if (lane >= d) x += y;
    }
    if (lane == 63) wsum[wv] = x;
    __syncthreads();
    if (tid == 0){
      int s = carry;
      #pragma unroll
      for (int k = 0; k < 16; ++k){ int t = wsum[k]; wsum[k] = s; s += t; }
      carry = s;
    }
    __syncthreads();
    int excl = wsum[wv] + x - v;
    if (i < n){ off[i] = excl; cur[i] = excl; }
    __syncthreads();
  }
  if (tid == 0) off[n] = carry;
}

__global__ void fill_kernel(const int* __restrict__ src, const int* __restrict__ dst,
                            int E, int* __restrict__ cur, int* __restrict__ lst){
  int i = blockIdx.x*blockDim.x + threadIdx.x;
  if (i < E){
    int d = dst[i];
    int p = atomicAdd(&cur[d], 1);
    lst[p] = src[i];
  }
}

// ---- pack W [K][N] f32 into MFMA-B fragment-linear bf16 ----
// chunk c = ((s*(N/16) + f)*64 + lane): 8 bf16 = B[col=f*16+(lane&15)][k=s*32+(lane>>4)*8 ..+8]
__global__ void wpack(const float* __restrict__ W, u16* __restrict__ out, int K, int N){
  int c = blockIdx.x*256 + threadIdx.x;
  int total = (K>>5)*(N>>4)*64;
  if (c >= total) return;
  int lane = c & 63;
  int f = (c >> 6) % (N>>4);
  int s = (c >> 6) / (N>>4);
  int col = f*16 + (lane & 15);
  int k0 = s*32 + (lane >> 4)*8;
  u16* o = out + (size_t)c*8;
  #pragma unroll
  for (int e = 0; e < 8; ++e) o[e] = f2b(W[(size_t)(k0+e)*N + col]);
}

// ---- barrier-free strip GEMM: C[M,N] = A[M,K] @ W[K,N] + bias ----
// One wave owns 32 rows (2 M-frags) x all N columns. No LDS, no __syncthreads.
// A: f32 (ABF=false) or bf16, row-major, streamed from HBM into regs.
// BPK: fragment-packed bf16 (wpack layout), L2-resident, read per k-step.
template<int K, int N, bool ABF, bool RELU, bool OBF>
__global__ __launch_bounds__(256, 2) void gemm_strip(const void* __restrict__ Av,
    const u16* __restrict__ BPK, const float* __restrict__ bias,
    void* __restrict__ Cv, int M, int nstrips)
{
  constexpr int NT = K/32, NF = N/16;
  const int wid = (blockIdx.x*256 + threadIdx.x) >> 6;
  if (wid >= nstrips) return;
  const int lane = threadIdx.x & 63;
  const int m15 = lane & 15, kg = lane >> 4;
  const int r0 = wid*32;
  // clamped load rows (stores are guarded instead)
  const int c0 = min(r0 + m15, M-1);
  const int c1 = min(r0 + 16 + m15, M-1);

  f32x4 acc[2][NF] = {};

  #pragma unroll
  for (int t = 0; t < NT; ++t){
    s16x8 a0, a1;
    if (ABF){
      a0 = *(const s16x8*)((const u16*)Av + (size_t)c0*K + t*32 + kg*8);
      a1 = *(const s16x8*)((const u16*)Av + (size_t)c1*K + t*32 + kg*8);
    } else {
      const float* p0 = (const float*)Av + (size_t)c0*K + t*32 + kg*8;
      const float* p1 = (const float*)Av + (size_t)c1*K + t*32 + kg*8;
      float4 x0 = ((const float4*)p0)[0], y0 = ((const float4*)p0)[1];
      float4 x1 = ((const float4*)p1)[0], y1 = ((const float4*)p1)[1];
      a0[0]=(short)f2b(x0.x); a0[1]=(short)f2b(x0.y); a0[2]=(short)f2b(x0.z); a0[3]=(short)f2b(x0.w);
      a0[4]=(short)f2b(y0.x); a0[5]=(short)f2b(y0.y); a0[6]=(short)f2b(y0.z); a0[7]=(short)f2b(y0.w);
      a1[0]=(short)f2b(x1.x); a1[1]=(short)f2b(x1.y); a1[2]=(short)f2b(x1.z); a1[3]=(short)f2b(x1.w);
      a1[4]=(short)f2b(y1.x); a1[5]=(short)f2b(y1.y); a1[6]=(short)f2b(y1.z); a1[7]=(short)f2b(y1.w);
    }
    const u16* bp = BPK + ((size_t)t*NF*64 + lane)*8;
    #pragma unroll
    for (int j = 0; j < NF; ++j){
      s16x8 b = *(const s16x8*)(bp + (size_t)j*64*8);
      acc[0][j] = __builtin_amdgcn_mfma_f32_16x16x32_bf16(a0, b, acc[0][j], 0, 0, 0);
      acc[1][j] = __builtin_amdgcn_mfma_f32_16x16x32_bf16(a1, b, acc[1][j], 0, 0, 0);
    }
  }

  // epilogue: row = r0 + 16*m + kg*4 + q, col = 16*j + m15
  #pragma unroll
  for (int j = 0; j < NF; ++j){
    int col = j*16 + m15;
    float bv = bias[col];
    #pragma unroll
    for (int m = 0; m < 2; ++m){
      int rbase = r0 + 16*m + kg*4;
      #pragma unroll
      for (int q = 0; q < 4; ++q){
        int row = rbase + q;
        if (row < M){
          float v = acc[m][j][q] + bv;
          if (RELU) v = fmaxf(v, 0.f);
          if (OBF) ((u16*)Cv)[(size_t)row*N + col] = f2b(v);
          else     ((float*)Cv)[(size_t)row*N + col] = v;
        }
      }
    }
  }
}

// ---- CSR pull aggregation: out[d] = ri[d] * sum_e so[src_e]*X[src_e], 256-dim bf16 ----
__global__ __launch_bounds__(256) void agg_kernel(const u16* __restrict__ X,
    const int* __restrict__ off, const int* __restrict__ lst,
    const float* __restrict__ so, const float* __restrict__ ri,
    u16* __restrict__ out, int nd)
{
  int lane = threadIdx.x & 63, wv = threadIdx.x >> 6;
  int d = blockIdx.x*4 + wv;
  if (d >= nd) return;
  int e0 = off[d], e1 = off[d+1];
  float a0=0.f, a1=0.f, a2=0.f, a3=0.f;
  for (int e = e0; e < e1; ++e){
    int s = lst[e];
    float sc = so[s];
    ushort4 u = ((const ushort4*)X)[(size_t)s*64 + lane];
    a0 = fmaf(b2f(u.x), sc, a0);
    a1 = fmaf(b2f(u.y), sc, a1);
    a2 = fmaf(b2f(u.z), sc, a2);
    a3 = fmaf(b2f(u.w), sc, a3);
  }
  float r = ri[d];
  ushort4 o;
  o.x = f2b(a0*r); o.y = f2b(a1*r); o.z = f2b(a2*r); o.w = f2b(a3*r);
  ((ushort4*)out)[(size_t)d*64 + lane] = o;
}

// ---- LayerNorm over 256 cols, in-place bf16, one wave per row ----
__global__ __launch_bounds__(256) void ln_kernel(u16* __restrict__ H,
    const float* __restrict__ g, const float* __restrict__ b, int n)
{
  int lane = threadIdx.x & 63, wv = threadIdx.x >> 6;
  int r = blockIdx.x*4 + wv;
  if (r >= n) return;
  ushort4 u = ((const ushort4*)H)[(size_t)r*64 + lane];
  float x0=b2f(u.x), x1=b2f(u.y), x2=b2f(u.z), x3=b2f(u.w);
  float s = x0+x1+x2+x3;
  #pragma unroll
  for (int d=1; d<64; d<<=1) s += __shfl_xor(s, d);
  float mu = s * (1.f/256.f);
  float d0=x0-mu, d1=x1-mu, d2=x2-mu, d3=x3-mu;
  float v = d0*d0 + d1*d1 + d2*d2 + d3*d3;
  #pragma unroll
  for (int d=1; d<64; d<<=1) v += __shfl_xor(v, d);
  float inv = rsqrtf(v*(1.f/256.f) + 1e-5f);
  float4 gv = ((const float4*)g)[lane];
  float4 bv = ((const float4*)b)[lane];
  ushort4 o;
  o.x = f2b(d0*inv*gv.x + bv.x);
  o.y = f2b(d1*inv*gv.y + bv.y);
  o.z = f2b(d2*inv*gv.z + bv.z);
  o.w = f2b(d3*inv*gv.w + bv.w);
  ((ushort4*)H)[(size_t)r*64 + lane] = o;
}

// ---- row L2-normalize, 128 cols, one wave per row ----
__global__ __launch_bounds__(256) void rownorm_kernel(const float* __restrict__ T,
    float* __restrict__ out, int n)
{
  int lane = threadIdx.x & 63, wv = threadIdx.x >> 6;
  int r = blockIdx.x*4 + wv;
  if (r >= n) return;
  float2 x = ((const float2*)T)[(size_t)r*64 + lane];
  float s = x.x*x.x + x.y*x.y;
  #pragma unroll
  for (int d=1; d<64; d<<=1) s += __shfl_xor(s, d);
  float nrm = sqrtf(s);
  float sc = 1.f / fmaxf(nrm, 1e-12f);
  float2 o; o.x = x.x*sc; o.y = x.y*sc;
  ((float2*)out)[(size_t)r*64 + lane] = o;
}

extern "C" void kernel_launch(void* const* d_in, const int* in_sizes, int n_in,
                              void* d_out, int out_size, void* d_ws, size_t ws_size,
                              hipStream_t stream)
{
  const float* feats = (const float*)d_in[0];
  const int*   b0s   = (const int*)d_in[1];
  const int*   b0d   = (const int*)d_in[2];
  const int*   b1s   = (const int*)d_in[3];
  const int*   b1d   = (const int*)d_in[4];
  const float* W1    = (const float*)d_in[5];
  const float* bias1 = (const float*)d_in[6];
  const float* Wc    = (const float*)d_in[7];
  const float* bc    = (const float*)d_in[8];
  const float* lng   = (const float*)d_in[9];
  const float* lnb   = (const float*)d_in[10];
  const float* Wo    = (const float*)d_in[11];
  const float* bo    = (const float*)d_in[12];
  const int E0 = in_sizes[1];
  const int E1 = in_sizes[3];
  (void)n_in; (void)out_size; (void)ws_size;

  char* p = (char*)d_ws;
  auto alloc = [&](size_t bytes)->void*{ void* q = (void*)p; p += (bytes + 255) & ~(size_t)255; return q; };
  u16*   g1   = (u16*)  alloc((size_t)NN0*HD*2);     // GEMM1 out; reused for conv1 out + LN
  u16*   hb   = (u16*)  alloc((size_t)NN1*HD*2);     // agg1 out
  u16*   ag2  = (u16*)  alloc((size_t)NN2*HD*2);
  float* c2   = (float*)alloc((size_t)NN2*OUT_D*4);
  u16*   W1P  = (u16*)  alloc((size_t)HD*IN_DIM*2);
  u16*   WcP  = (u16*)  alloc((size_t)HD*HD*2);
  u16*   WoP  = (u16*)  alloc((size_t)OUT_D*HD*2);
  char* cnt_begin = p;
  int* outc0 = (int*)alloc((size_t)NN0*4);
  int* inc0  = (int*)alloc((size_t)NN1*4);
  int* outc1 = (int*)alloc((size_t)NN1*4);
  int* inc1  = (int*)alloc((size_t)NN2*4);
  char* cnt_end = p;
  float* so0 = (float*)alloc((size_t)NN0*4);
  float* ri0 = (float*)alloc((size_t)NN1*4);
  float* so1 = (float*)alloc((size_t)NN1*4);
  float* ri1 = (float*)alloc((size_t)NN2*4);
  int* off0  = (int*)alloc((size_t)(NN1+1)*4);
  int* cur0  = (int*)alloc((size_t)NN1*4);
  int* off1  = (int*)alloc((size_t)(NN2+1)*4);
  int* cur1  = (int*)alloc((size_t)NN2*4);
  int* lst0  = (int*)alloc((size_t)800000*4);
  int* lst1  = (int*)alloc((size_t)160000*4);

  hipMemsetAsync(cnt_begin, 0, (size_t)(cnt_end - cnt_begin), stream);

  // graph prep
  deg_count<<<(E0+255)/256, 256, 0, stream>>>(b0s, b0d, E0, outc0, inc0);
  deg_count<<<(E1+255)/256, 256, 0, stream>>>(b1s, b1d, E1, outc1, inc1);
  mkscale<<<(NN0+255)/256, 256, 0, stream>>>(outc0, so0, NN0);
  mkscale<<<(NN1+255)/256, 256, 0, stream>>>(inc0,  ri0, NN1);
  mkscale<<<(NN1+255)/256, 256, 0, stream>>>(outc1, so1, NN1);
  mkscale<<<(NN2+255)/256, 256, 0, stream>>>(inc1,  ri1, NN2);
  scan_kernel<<<1, 1024, 0, stream>>>(inc0, off0, cur0, NN1);
  scan_kernel<<<1, 1024, 0, stream>>>(inc1, off1, cur1, NN2);
  fill_kernel<<<(E0+255)/256, 256, 0, stream>>>(b0s, b0d, E0, cur0, lst0);
  fill_kernel<<<(E1+255)/256, 256, 0, stream>>>(b1s, b1d, E1, cur1, lst1);

  // weight fragment-packing (tiny)
  wpack<<<((IN_DIM/32)*(HD/16)*64 + 255)/256, 256, 0, stream>>>(W1, W1P, IN_DIM, HD);
  wpack<<<((HD/32)*(HD/16)*64 + 255)/256, 256, 0, stream>>>(Wc, WcP, HD, HD);
  wpack<<<((HD/32)*(OUT_D/16)*64 + 255)/256, 256, 0, stream>>>(Wo, WoP, HD, OUT_D);

  // h = feats @ W1 + bias1   [200000,512]@[512,256] -> g1 (bf16)
  {
    int nstrips = (NN0 + 31) / 32;            // 6250
    int nblk = (nstrips + 3) / 4;
    gemm_strip<IN_DIM, HD, false, false, true><<<nblk, 256, 0, stream>>>(feats, W1P, bias1, g1, NN0, nstrips);
  }
  // agg1 over b0 -> hb
  agg_kernel<<<(NN1+3)/4, 256, 0, stream>>>(g1, off0, lst0, so0, ri0, hb, NN1);
  // conv1 = relu(agg1 @ Wc + bc)  [50000,256]@[256,256] -> g1 (region reuse; hb intact)
  {
    int nstrips = (NN1 + 31) / 32;            // 1563
    int nblk = (nstrips + 3) / 4;
    gemm_strip<HD, HD, true, true, true><<<nblk, 256, 0, stream>>>(hb, WcP, bc, g1, NN1, nstrips);
  }
  // LayerNorm in-place on g1[0:NN1]
  ln_kernel<<<(NN1+3)/4, 256, 0, stream>>>(g1, lng, lnb, NN1);
  // agg2 over b1 -> ag2
  agg_kernel<<<(NN2+3)/4, 256, 0, stream>>>(g1, off1, lst1, so1, ri1, ag2, NN2);
  // conv2 = agg2 @ Wo + bo  [10000,256]@[256,128] -> c2 (f32)
  {
    int nstrips = (NN2 + 31) / 32;            // 313
    int nblk = (nstrips + 3) / 4;
    gemm_strip<HD, OUT_D, true, false, false><<<nblk, 256, 0, stream>>>(ag2, WoP, bo, c2, NN2, nstrips);
  }
  // row L2 normalize -> d_out (f32)
  rownorm_kernel<<<(NN2+3)/4, 256, 0, stream>>>(c2, (float*)d_out, NN2);
}

// Round 5
// 597.078 us; speedup vs baseline: 1.4116x; 1.4116x over previous
//
#include <hip/hip_runtime.h>
#include <hip/hip_bf16.h>

#define NN0 200000
#define NN1 50000
#define NN2 10000
#define IN_DIM 512
#define HD 256
#define OUT_D 128

typedef unsigned short u16;
typedef unsigned int u32;
typedef __attribute__((ext_vector_type(8))) short s16x8;
typedef __attribute__((ext_vector_type(4))) float f32x4;

__device__ __forceinline__ float b2f(u16 u){ return __uint_as_float(((u32)u)<<16); }
__device__ __forceinline__ u16 f2b(float f){
  u32 x = __float_as_uint(f);
  u32 r = x + 0x7fffu + ((x>>16)&1u);
  return (u16)(r>>16);
}

// direct global->LDS 16B async copy. LDS dest: wave-uniform base + lane*16.
__device__ __forceinline__ void gl_lds16(const void* g, void* l){
  __builtin_amdgcn_global_load_lds((const __attribute__((address_space(1))) u32*)g,
                                   (__attribute__((address_space(3))) u32*)l, 16, 0, 0);
}

// ---- degree counting (int atomics) ----
__global__ void deg_count(const int* __restrict__ src, const int* __restrict__ dst,
                          int E, int* __restrict__ outc, int* __restrict__ inc){
  int i = blockIdx.x*blockDim.x + threadIdx.x;
  if (i < E){
    atomicAdd(&outc[src[i]], 1);
    atomicAdd(&inc[dst[i]], 1);
  }
}

__global__ void mkscale(const int* __restrict__ c, float* __restrict__ o, int n){
  int i = blockIdx.x*blockDim.x + threadIdx.x;
  if (i < n) o[i] = rsqrtf((float)(c[i] > 1 ? c[i] : 1));
}

// ---- exclusive scan (single block, shuffle-based) ----
__global__ __launch_bounds__(1024) void scan_kernel(const int* __restrict__ cnt,
    int* __restrict__ off, int* __restrict__ cur, int n){
  __shared__ int wsum[16];
  int tid = threadIdx.x, lane = tid & 63, wv = tid >> 6;
  int carry = 0;
  for (int base = 0; base < n; base += 1024){
    int i = base + tid;
    int v = (i < n) ? cnt[i] : 0;
    int x = v;
    #pragma unroll
    for (int d = 1; d < 64; d <<= 1){
      int y = __shfl_up(x, d);
      if (lane >= d) x += y;
    }
    if (lane == 63) wsum[wv] = x;
    __syncthreads();
    if (tid == 0){
      int s = carry;
      #pragma unroll
      for (int k = 0; k < 16; ++k){ int t = wsum[k]; wsum[k] = s; s += t; }
      carry = s;
    }
    __syncthreads();
    int excl = wsum[wv] + x - v;
    if (i < n){ off[i] = excl; cur[i] = excl; }
    __syncthreads();
  }
  if (tid == 0) off[n] = carry;
}

__global__ void fill_kernel(const int* __restrict__ src, const int* __restrict__ dst,
                            int E, int* __restrict__ cur, int* __restrict__ lst){
  int i = blockIdx.x*blockDim.x + threadIdx.x;
  if (i < E){
    int d = dst[i];
    int p = atomicAdd(&cur[d], 1);
    lst[p] = src[i];
  }
}

// ---- pack W [K][N] f32 into MFMA-B fragment-linear bf16 ----
// chunk c = ((s*(N/16) + f)*64 + lane): 8 bf16 = B[col=f*16+(lane&15)][k=s*32+(lane>>4)*8 ..+8]
__global__ void wpack(const float* __restrict__ W, u16* __restrict__ out, int K, int N){
  int c = blockIdx.x*256 + threadIdx.x;
  int total = (K>>5)*(N>>4)*64;
  if (c >= total) return;
  int lane = c & 63;
  int f = (c >> 6) % (N>>4);
  int s = (c >> 6) / (N>>4);
  int col = f*16 + (lane & 15);
  int k0 = s*32 + (lane >> 4)*8;
  u16* o = out + (size_t)c*8;
  #pragma unroll
  for (int e = 0; e < 8; ++e) o[e] = f2b(W[(size_t)(k0+e)*N + col]);
}

// ---- MFMA GEMM with global_load_lds A-staging ----
// C[M,N] = A[M,K] @ W[K,N] + bias. A: f32 (ABF=false) or bf16 row-major.
// BPK: fragment-packed bf16 (wpack), L2-resident, read direct to regs.
// Tile 128x128, BK=64, A double-buffered in LDS via global_load_lds(16B),
// XOR-swizzled at 16B granularity (linear LDS dest, pre-swizzled global src,
// swizzled ds_read) -> conflict-free fragment reads. One barrier per K-tile.
template<int K, int N, bool ABF, bool RELU, bool OBF>
__global__ __launch_bounds__(256) void gemm_glds(const void* __restrict__ Av,
    const u16* __restrict__ BPK, const float* __restrict__ bias,
    void* __restrict__ Cv, int M)
{
  constexpr int ESZ   = ABF ? 2 : 4;
  constexpr int SLOTS = (64*ESZ)/16;       // 16B slots per 64-elem row: 8 (bf16) / 16 (f32)
  constexpr int SMSK  = SLOTS - 1;
  constexpr int ROWB  = 64*ESZ;            // row bytes: 128 / 256
  constexpr int TILEB = 128*64*ESZ;        // 16 KB / 32 KB
  constexpr int IW    = TILEB/1024/4;      // glds instrs per wave: 4 / 8
  constexpr int NT    = K/64;
  constexpr int NF16  = N/16;
  constexpr int NYB   = N/128;
  constexpr int LDSB  = (2*TILEB > 34816) ? 2*TILEB : 34816;
  __shared__ char smem[LDSB];

  const int t = threadIdx.x;
  const int lane = t & 63;
  const int wv = t >> 6;
  const int wr = wv >> 1, wc = wv & 1;
  const int b  = blockIdx.x;
  const int by = b % NYB;
  const int r0 = (b / NYB) * 128;
  const int c0 = by * 128;
  const int m15 = lane & 15, kg = lane >> 4;

  auto stage = [&](int buf, int ti){
    const int k0 = ti*64;
    char* bb = smem + buf*TILEB;
    #pragma unroll
    for (int s = 0; s < IW; ++s){
      int i16 = (wv*IW + s)*64 + lane;
      int row = i16 / SLOTS;
      int tt  = i16 & SMSK;
      int tsrc = tt ^ (row & SMSK);
      int grc = min(r0 + row, M-1);
      const char* g = (const char*)Av + ((size_t)grc*K + k0)*ESZ + tsrc*16;
      gl_lds16(g, bb + (wv*IW + s)*1024);
    }
  };

  f32x4 acc[4][4] = {};

  stage(0, 0);
  __syncthreads();

  for (int ti = 0; ti < NT; ++ti){
    if (ti + 1 < NT) stage((ti+1)&1, ti+1);

    // B fragments direct from L2 (packed linear per wpack)
    s16x8 bfr[2][4];
    #pragma unroll
    for (int kh = 0; kh < 2; ++kh)
      #pragma unroll
      for (int j = 0; j < 4; ++j)
        bfr[kh][j] = *(const s16x8*)(BPK +
          (((size_t)(2*ti+kh)*NF16 + by*8 + wc*4 + j)*64 + lane)*8);

    const char* bb = smem + (ti&1)*TILEB;
    s16x8 afr[2][4];
    #pragma unroll
    for (int kh = 0; kh < 2; ++kh){
      #pragma unroll
      for (int i = 0; i < 4; ++i){
        int row_l = wr*64 + i*16 + m15;
        if (ABF){
          int s = kh*4 + kg;
          int sw = s ^ (row_l & SMSK);
          afr[kh][i] = *(const s16x8*)(bb + row_l*ROWB + sw*16);
        } else {
          int s0 = kh*8 + kg*2;
          int sw0 = s0 ^ (row_l & SMSK);
          int sw1 = (s0+1) ^ (row_l & SMSK);
          float4 lo = *(const float4*)(bb + row_l*ROWB + sw0*16);
          float4 hi = *(const float4*)(bb + row_l*ROWB + sw1*16);
          s16x8 v;
          v[0]=(short)f2b(lo.x); v[1]=(short)f2b(lo.y); v[2]=(short)f2b(lo.z); v[3]=(short)f2b(lo.w);
          v[4]=(short)f2b(hi.x); v[5]=(short)f2b(hi.y); v[6]=(short)f2b(hi.z); v[7]=(short)f2b(hi.w);
          afr[kh][i] = v;
        }
      }
    }

    #pragma unroll
    for (int kh = 0; kh < 2; ++kh)
      #pragma unroll
      for (int i = 0; i < 4; ++i)
        #pragma unroll
        for (int j = 0; j < 4; ++j)
          acc[i][j] = __builtin_amdgcn_mfma_f32_16x16x32_bf16(afr[kh][i], bfr[kh][j], acc[i][j], 0, 0, 0);

    __syncthreads();   // drains staged loads (next buf ready) + ds_reads (cur buf reusable)
  }

  if (OBF){
    // repack epilogue: acc -> LDS u16 [128][136] -> coalesced 16B stores
    u16* cs = (u16*)smem;
    #pragma unroll
    for (int j = 0; j < 4; ++j){
      int colg = c0 + wc*64 + j*16 + m15;
      float bv = bias[colg];
      #pragma unroll
      for (int i = 0; i < 4; ++i){
        int rl = wr*64 + i*16 + kg*4;
        #pragma unroll
        for (int q = 0; q < 4; ++q){
          float v = acc[i][j][q] + bv;
          if (RELU) v = fmaxf(v, 0.f);
          cs[(rl+q)*136 + wc*64 + j*16 + m15] = f2b(v);
        }
      }
    }
    __syncthreads();
    int rr = t >> 1, hh = t & 1;
    int go = r0 + rr;
    if (go < M){
      u16* dst = (u16*)Cv + (size_t)go*N + c0 + hh*64;
      const u16* sp = &cs[rr*136 + hh*64];
      #pragma unroll
      for (int c = 0; c < 8; ++c) *(s16x8*)(dst + c*8) = *(const s16x8*)(sp + c*8);
    }
  } else {
    #pragma unroll
    for (int j = 0; j < 4; ++j){
      int colg = c0 + wc*64 + j*16 + m15;
      float bv = bias[colg];
      #pragma unroll
      for (int i = 0; i < 4; ++i){
        int rbase = r0 + wr*64 + i*16 + kg*4;
        #pragma unroll
        for (int q = 0; q < 4; ++q){
          int row = rbase + q;
          if (row < M){
            float v = acc[i][j][q] + bv;
            if (RELU) v = fmaxf(v, 0.f);
            ((float*)Cv)[(size_t)row*N + colg] = v;
          }
        }
      }
    }
  }
}

// ---- CSR pull aggregation, 4x-unrolled edge loop for memory-level parallelism ----
__global__ __launch_bounds__(256) void agg_kernel(const u16* __restrict__ X,
    const int* __restrict__ off, const int* __restrict__ lst,
    const float* __restrict__ so, const float* __restrict__ ri,
    u16* __restrict__ out, int nd)
{
  int lane = threadIdx.x & 63, wv = threadIdx.x >> 6;
  int d = blockIdx.x*4 + wv;
  if (d >= nd) return;
  int e0 = off[d], e1 = off[d+1];
  float a0=0.f, a1=0.f, a2=0.f, a3=0.f;
  int e = e0;
  for (; e + 4 <= e1; e += 4){
    int s0 = lst[e], s1 = lst[e+1], s2 = lst[e+2], s3 = lst[e+3];
    float c0 = so[s0], c1 = so[s1], c2 = so[s2], c3 = so[s3];
    ushort4 u0 = ((const ushort4*)X)[(size_t)s0*64 + lane];
    ushort4 u1 = ((const ushort4*)X)[(size_t)s1*64 + lane];
    ushort4 u2 = ((const ushort4*)X)[(size_t)s2*64 + lane];
    ushort4 u3 = ((const ushort4*)X)[(size_t)s3*64 + lane];
    a0 = fmaf(b2f(u0.x), c0, a0); a1 = fmaf(b2f(u0.y), c0, a1);
    a2 = fmaf(b2f(u0.z), c0, a2); a3 = fmaf(b2f(u0.w), c0, a3);
    a0 = fmaf(b2f(u1.x), c1, a0); a1 = fmaf(b2f(u1.y), c1, a1);
    a2 = fmaf(b2f(u1.z), c1, a2); a3 = fmaf(b2f(u1.w), c1, a3);
    a0 = fmaf(b2f(u2.x), c2, a0); a1 = fmaf(b2f(u2.y), c2, a1);
    a2 = fmaf(b2f(u2.z), c2, a2); a3 = fmaf(b2f(u2.w), c2, a3);
    a0 = fmaf(b2f(u3.x), c3, a0); a1 = fmaf(b2f(u3.y), c3, a1);
    a2 = fmaf(b2f(u3.z), c3, a2); a3 = fmaf(b2f(u3.w), c3, a3);
  }
  for (; e < e1; ++e){
    int s = lst[e];
    float sc = so[s];
    ushort4 u = ((const ushort4*)X)[(size_t)s*64 + lane];
    a0 = fmaf(b2f(u.x), sc, a0);
    a1 = fmaf(b2f(u.y), sc, a1);
    a2 = fmaf(b2f(u.z), sc, a2);
    a3 = fmaf(b2f(u.w), sc, a3);
  }
  float r = ri[d];
  ushort4 o;
  o.x = f2b(a0*r); o.y = f2b(a1*r); o.z = f2b(a2*r); o.w = f2b(a3*r);
  ((ushort4*)out)[(size_t)d*64 + lane] = o;
}

// ---- LayerNorm over 256 cols, in-place bf16, one wave per row ----
__global__ __launch_bounds__(256) void ln_kernel(u16* __restrict__ H,
    const float* __restrict__ g, const float* __restrict__ b, int n)
{
  int lane = threadIdx.x & 63, wv = threadIdx.x >> 6;
  int r = blockIdx.x*4 + wv;
  if (r >= n) return;
  ushort4 u = ((const ushort4*)H)[(size_t)r*64 + lane];
  float x0=b2f(u.x), x1=b2f(u.y), x2=b2f(u.z), x3=b2f(u.w);
  float s = x0+x1+x2+x3;
  #pragma unroll
  for (int d=1; d<64; d<<=1) s += __shfl_xor(s, d);
  float mu = s * (1.f/256.f);
  float d0=x0-mu, d1=x1-mu, d2=x2-mu, d3=x3-mu;
  float v = d0*d0 + d1*d1 + d2*d2 + d3*d3;
  #pragma unroll
  for (int d=1; d<64; d<<=1) v += __shfl_xor(v, d);
  float inv = rsqrtf(v*(1.f/256.f) + 1e-5f);
  float4 gv = ((const float4*)g)[lane];
  float4 bv = ((const float4*)b)[lane];
  ushort4 o;
  o.x = f2b(d0*inv*gv.x + bv.x);
  o.y = f2b(d1*inv*gv.y + bv.y);
  o.z = f2b(d2*inv*gv.z + bv.z);
  o.w = f2b(d3*inv*gv.w + bv.w);
  ((ushort4*)H)[(size_t)r*64 + lane] = o;
}

// ---- row L2-normalize, 128 cols, one wave per row ----
__global__ __launch_bounds__(256) void rownorm_kernel(const float* __restrict__ T,
    float* __restrict__ out, int n)
{
  int lane = threadIdx.x & 63, wv = threadIdx.x >> 6;
  int r = blockIdx.x*4 + wv;
  if (r >= n) return;
  float2 x = ((const float2*)T)[(size_t)r*64 + lane];
  float s = x.x*x.x + x.y*x.y;
  #pragma unroll
  for (int d=1; d<64; d<<=1) s += __shfl_xor(s, d);
  float nrm = sqrtf(s);
  float sc = 1.f / fmaxf(nrm, 1e-12f);
  float2 o; o.x = x.x*sc; o.y = x.y*sc;
  ((float2*)out)[(size_t)r*64 + lane] = o;
}

extern "C" void kernel_launch(void* const* d_in, const int* in_sizes, int n_in,
                              void* d_out, int out_size, void* d_ws, size_t ws_size,
                              hipStream_t stream)
{
  const float* feats = (const float*)d_in[0];
  const int*   b0s   = (const int*)d_in[1];
  const int*   b0d   = (const int*)d_in[2];
  const int*   b1s   = (const int*)d_in[3];
  const int*   b1d   = (const int*)d_in[4];
  const float* W1    = (const float*)d_in[5];
  const float* bias1 = (const float*)d_in[6];
  const float* Wc    = (const float*)d_in[7];
  const float* bc    = (const float*)d_in[8];
  const float* lng   = (const float*)d_in[9];
  const float* lnb   = (const float*)d_in[10];
  const float* Wo    = (const float*)d_in[11];
  const float* bo    = (const float*)d_in[12];
  const int E0 = in_sizes[1];
  const int E1 = in_sizes[3];
  (void)n_in; (void)out_size; (void)ws_size;

  char* p = (char*)d_ws;
  auto alloc = [&](size_t bytes)->void*{ void* q = (void*)p; p += (bytes + 255) & ~(size_t)255; return q; };
  u16*   g1   = (u16*)  alloc((size_t)NN0*HD*2);     // GEMM1 out; reused for conv1 out + LN
  u16*   hb   = (u16*)  alloc((size_t)NN1*HD*2);     // agg1 out
  u16*   ag2  = (u16*)  alloc((size_t)NN2*HD*2);
  float* c2   = (float*)alloc((size_t)NN2*OUT_D*4);
  u16*   W1P  = (u16*)  alloc((size_t)HD*IN_DIM*2);
  u16*   WcP  = (u16*)  alloc((size_t)HD*HD*2);
  u16*   WoP  = (u16*)  alloc((size_t)OUT_D*HD*2);
  char* cnt_begin = p;
  int* outc0 = (int*)alloc((size_t)NN0*4);
  int* inc0  = (int*)alloc((size_t)NN1*4);
  int* outc1 = (int*)alloc((size_t)NN1*4);
  int* inc1  = (int*)alloc((size_t)NN2*4);
  char* cnt_end = p;
  float* so0 = (float*)alloc((size_t)NN0*4);
  float* ri0 = (float*)alloc((size_t)NN1*4);
  float* so1 = (float*)alloc((size_t)NN1*4);
  float* ri1 = (float*)alloc((size_t)NN2*4);
  int* off0  = (int*)alloc((size_t)(NN1+1)*4);
  int* cur0  = (int*)alloc((size_t)NN1*4);
  int* off1  = (int*)alloc((size_t)(NN2+1)*4);
  int* cur1  = (int*)alloc((size_t)NN2*4);
  int* lst0  = (int*)alloc((size_t)800000*4);
  int* lst1  = (int*)alloc((size_t)160000*4);

  hipMemsetAsync(cnt_begin, 0, (size_t)(cnt_end - cnt_begin), stream);

  // graph prep
  deg_count<<<(E0+255)/256, 256, 0, stream>>>(b0s, b0d, E0, outc0, inc0);
  deg_count<<<(E1+255)/256, 256, 0, stream>>>(b1s, b1d, E1, outc1, inc1);
  mkscale<<<(NN0+255)/256, 256, 0, stream>>>(outc0, so0, NN0);
  mkscale<<<(NN1+255)/256, 256, 0, stream>>>(inc0,  ri0, NN1);
  mkscale<<<(NN1+255)/256, 256, 0, stream>>>(outc1, so1, NN1);
  mkscale<<<(NN2+255)/256, 256, 0, stream>>>(inc1,  ri1, NN2);
  scan_kernel<<<1, 1024, 0, stream>>>(inc0, off0, cur0, NN1);
  scan_kernel<<<1, 1024, 0, stream>>>(inc1, off1, cur1, NN2);
  fill_kernel<<<(E0+255)/256, 256, 0, stream>>>(b0s, b0d, E0, cur0, lst0);
  fill_kernel<<<(E1+255)/256, 256, 0, stream>>>(b1s, b1d, E1, cur1, lst1);

  // weight fragment-packing (tiny)
  wpack<<<((IN_DIM/32)*(HD/16)*64 + 255)/256, 256, 0, stream>>>(W1, W1P, IN_DIM, HD);
  wpack<<<((HD/32)*(HD/16)*64 + 255)/256, 256, 0, stream>>>(Wc, WcP, HD, HD);
  wpack<<<((HD/32)*(OUT_D/16)*64 + 255)/256, 256, 0, stream>>>(Wo, WoP, HD, OUT_D);

  // h = feats @ W1 + bias1   [200000,512]@[512,256] -> g1 (bf16)
  {
    int nblk = ((NN0+127)/128) * (HD/128);   // 1563 * 2, N-halves interleaved for A L2-reuse
    gemm_glds<IN_DIM, HD, false, false, true><<<nblk, 256, 0, stream>>>(feats, W1P, bias1, g1, NN0);
  }
  // agg1 over b0 -> hb
  agg_kernel<<<(NN1+3)/4, 256, 0, stream>>>(g1, off0, lst0, so0, ri0, hb, NN1);
  // conv1 = relu(agg1 @ Wc + bc)  [50000,256]@[256,256] -> g1 (region reuse; hb intact)
  {
    int nblk = ((NN1+127)/128) * (HD/128);
    gemm_glds<HD, HD, true, true, true><<<nblk, 256, 0, stream>>>(hb, WcP, bc, g1, NN1);
  }
  // LayerNorm in-place on g1[0:NN1]
  ln_kernel<<<(NN1+3)/4, 256, 0, stream>>>(g1, lng, lnb, NN1);
  // agg2 over b1 -> ag2
  agg_kernel<<<(NN2+3)/4, 256, 0, stream>>>(g1, off1, lst1, so1, ri1, ag2, NN2);
  // conv2 = agg2 @ Wo + bo  [10000,256]@[256,128] -> c2 (f32)
  {
    int nblk = ((NN2+127)/128) * (OUT_D/128);
    gemm_glds<HD, OUT_D, true, false, false><<<nblk, 256, 0, stream>>>(ag2, WoP, bo, c2, NN2);
  }
  // row L2 normalize -> d_out (f32)
  rownorm_kernel<<<(NN2+3)/4, 256, 0, stream>>>(c2, (float*)d_out, NN2);
}

// Round 6
// 478.268 us; speedup vs baseline: 1.7623x; 1.2484x over previous
//
#include <hip/hip_runtime.h>
#include <hip/hip_bf16.h>

#define NN0 200000
#define NN1 50000
#define NN2 10000
#define IN_DIM 512
#define HD 256
#define OUT_D 128

typedef unsigned short u16;
typedef unsigned int u32;
typedef __attribute__((ext_vector_type(8))) short s16x8;
typedef __attribute__((ext_vector_type(4))) float f32x4;

__device__ __forceinline__ float b2f(u16 u){ return __uint_as_float(((u32)u)<<16); }
__device__ __forceinline__ u16 f2b(float f){
  u32 x = __float_as_uint(f);
  u32 r = x + 0x7fffu + ((x>>16)&1u);
  return (u16)(r>>16);
}

// direct global->LDS 16B async copy. LDS dest: wave-uniform base + lane*16.
__device__ __forceinline__ void gl_lds16(const void* g, void* l){
  __builtin_amdgcn_global_load_lds((const __attribute__((address_space(1))) u32*)g,
                                   (__attribute__((address_space(3))) u32*)l, 16, 0, 0);
}

// ---- fused degree counting for both graphs ----
__global__ void prep_deg(const int* __restrict__ s0, const int* __restrict__ d0, int E0,
                         const int* __restrict__ s1, const int* __restrict__ d1, int E1,
                         int* __restrict__ outc0, int* __restrict__ inc0,
                         int* __restrict__ outc1, int* __restrict__ inc1){
  int i = blockIdx.x*blockDim.x + threadIdx.x;
  if (i < E0){ atomicAdd(&outc0[s0[i]], 1); atomicAdd(&inc0[d0[i]], 1); }
  if (i < E1){ atomicAdd(&outc1[s1[i]], 1); atomicAdd(&inc1[d1[i]], 1); }
}

// ---- fused rsqrt-degree scales ----
__global__ void prep_scale(const int* __restrict__ outc0, float* __restrict__ so0,
                           const int* __restrict__ inc0,  float* __restrict__ ri0,
                           const int* __restrict__ outc1, float* __restrict__ so1,
                           const int* __restrict__ inc1,  float* __restrict__ ri1){
  int i = blockIdx.x*blockDim.x + threadIdx.x;
  if (i < NN0) so0[i] = rsqrtf((float)(outc0[i] > 1 ? outc0[i] : 1));
  if (i < NN1){
    ri0[i] = rsqrtf((float)(inc0[i]  > 1 ? inc0[i]  : 1));
    so1[i] = rsqrtf((float)(outc1[i] > 1 ? outc1[i] : 1));
  }
  if (i < NN2) ri1[i] = rsqrtf((float)(inc1[i] > 1 ? inc1[i] : 1));
}

// ---- exclusive scan (single block per graph, shuffle-based) ----
__device__ void scan_dev(const int* __restrict__ cnt, int* __restrict__ off,
                         int* __restrict__ cur, int n){
  __shared__ int wsum[16];
  int tid = threadIdx.x, lane = tid & 63, wv = tid >> 6;
  int carry = 0;
  for (int base = 0; base < n; base += 1024){
    int i = base + tid;
    int v = (i < n) ? cnt[i] : 0;
    int x = v;
    #pragma unroll
    for (int d = 1; d < 64; d <<= 1){
      int y = __shfl_up(x, d);
      if (lane >= d) x += y;
    }
    if (lane == 63) wsum[wv] = x;
    __syncthreads();
    if (tid == 0){
      int s = carry;
      #pragma unroll
      for (int k = 0; k < 16; ++k){ int t = wsum[k]; wsum[k] = s; s += t; }
      carry = s;
    }
    __syncthreads();
    int excl = wsum[wv] + x - v;
    if (i < n){ off[i] = excl; cur[i] = excl; }
    __syncthreads();
  }
  if (tid == 0) off[n] = carry;
}

__global__ __launch_bounds__(1024) void scan2_kernel(
    const int* c0, int* o0, int* u0, int n0,
    const int* c1, int* o1, int* u1, int n1){
  if (blockIdx.x == 0) scan_dev(c0, o0, u0, n0);
  else                 scan_dev(c1, o1, u1, n1);
}

// ---- fused CSR fill for both graphs ----
__global__ void fill2_kernel(const int* __restrict__ s0, const int* __restrict__ d0, int E0,
                             int* __restrict__ cur0, int* __restrict__ l0,
                             const int* __restrict__ s1, const int* __restrict__ d1, int E1,
                             int* __restrict__ cur1, int* __restrict__ l1){
  int i = blockIdx.x*blockDim.x + threadIdx.x;
  if (i < E0){ int d = d0[i]; l0[atomicAdd(&cur0[d], 1)] = s0[i]; }
  if (i < E1){ int d = d1[i]; l1[atomicAdd(&cur1[d], 1)] = s1[i]; }
}

// ---- pack W [K][N] f32 into MFMA-B fragment-linear bf16 ----
__device__ __forceinline__ void pack_one(const float* __restrict__ W, u16* __restrict__ out,
                                         int K, int N, int c){
  int lane = c & 63;
  int f = (c >> 6) % (N>>4);
  int s = (c >> 6) / (N>>4);
  int col = f*16 + (lane & 15);
  int k0 = s*32 + (lane >> 4)*8;
  u16* o = out + (size_t)c*8;
  #pragma unroll
  for (int e = 0; e < 8; ++e) o[e] = f2b(W[(size_t)(k0+e)*N + col]);
}

__global__ void wpack3(const float* W1, u16* P1, const float* Wc, u16* Pc,
                       const float* Wo, u16* Po){
  int c = blockIdx.x*256 + threadIdx.x;
  // totals: W1 (512x256)->16384, Wc (256x256)->8192, Wo (256x128)->4096
  if (c < 16384)      pack_one(W1, P1, IN_DIM, HD, c);
  else if (c < 24576) pack_one(Wc, Pc, HD, HD, c - 16384);
  else if (c < 28672) pack_one(Wo, Po, HD, OUT_D, c - 24576);
}

// ---- MFMA GEMM, global_load_lds A-staging, counted-vmcnt pipeline (T3/T4) ----
// C[M,N] = A[M,K] @ W[K,N] + bias. A: f32 (ABF=false) or bf16 row-major.
// BPK: fragment-packed bf16 (wpack), L2-resident. Tile 128x128, BK=64,
// A double-buffered via glds(16B), 16B-XOR swizzle (linear LDS dest,
// pre-swizzled global src, swizzled ds_read). Two raw barriers per tile,
// vmcnt never drained to 0 in-loop: stage(t+1) stays in flight.
template<int K, int N, bool ABF, bool RELU, bool OBF>
__global__ __launch_bounds__(256) void gemm_glds(const void* __restrict__ Av,
    const u16* __restrict__ BPK, const float* __restrict__ bias,
    void* __restrict__ Cv, int M)
{
  constexpr int ESZ   = ABF ? 2 : 4;
  constexpr int SLOTS = (64*ESZ)/16;       // 16B slots per 64-elem row: 8 / 16
  constexpr int SMSK  = SLOTS - 1;
  constexpr int ROWB  = 64*ESZ;
  constexpr int TILEB = 128*64*ESZ;        // 16 KB / 32 KB
  constexpr int IW    = TILEB/1024/4;      // glds per wave per stage: 4 / 8
  constexpr int NT    = K/64;
  constexpr int NF16  = N/16;
  constexpr int NYB   = N/128;
  constexpr int LDSB  = (2*TILEB > 34816) ? 2*TILEB : 34816;
  __shared__ char smem[LDSB];

  const int t = threadIdx.x;
  const int lane = t & 63;
  const int wv = t >> 6;
  const int wr = wv >> 1, wc = wv & 1;

  // XCD-bijective block swizzle (m204): contiguous logical chunks per XCD
  int b;
  {
    int nb = gridDim.x, h = blockIdx.x;
    if (nb >= 8){
      int q = nb >> 3, r = nb & 7, k = h & 7, pos = h >> 3;
      b = (k < r ? k*(q+1) : r*(q+1) + (k-r)*q) + pos;
    } else b = h;
  }
  const int by = b % NYB;
  const int r0 = (b / NYB) * 128;
  const int c0 = by * 128;
  const int m15 = lane & 15, kg = lane >> 4;

  auto stage = [&](int buf, int ti){
    const int k0 = ti*64;
    char* bb = smem + buf*TILEB;
    #pragma unroll
    for (int s = 0; s < IW; ++s){
      int i16 = (wv*IW + s)*64 + lane;
      int row = i16 / SLOTS;
      int tt  = i16 & SMSK;
      int tsrc = tt ^ (row & SMSK);
      int grc = min(r0 + row, M-1);
      const char* g = (const char*)Av + ((size_t)grc*K + k0)*ESZ + tsrc*16;
      gl_lds16(g, bb + (wv*IW + s)*1024);
    }
  };

  f32x4 acc[4][4] = {};

  stage(0, 0);

  for (int ti = 0; ti < NT; ++ti){
    // 1. B fragments (8 VMEM loads) — MUST precede stage for vmcnt accounting
    s16x8 bfr[2][4];
    #pragma unroll
    for (int kh = 0; kh < 2; ++kh)
      #pragma unroll
      for (int j = 0; j < 4; ++j)
        bfr[kh][j] = *(const s16x8*)(BPK +
          (((size_t)(2*ti+kh)*NF16 + by*8 + wc*4 + j)*64 + lane)*8);
    __builtin_amdgcn_sched_barrier(0);

    // 2. prefetch next tile (stays in flight across the barrier)
    if (ti + 1 < NT) stage((ti+1)&1, ti+1);
    __builtin_amdgcn_sched_barrier(0);

    // 3. wait for MY stage(ti) only (in-order vmcnt retire: all but newest N done)
    if (ti + 1 < NT){
      if constexpr (IW == 8) asm volatile("s_waitcnt vmcnt(16)");
      else                   asm volatile("s_waitcnt vmcnt(12)");
    } else {
      asm volatile("s_waitcnt vmcnt(8)");
    }
    __builtin_amdgcn_s_barrier();            // all waves' stage(ti) visible
    __builtin_amdgcn_sched_barrier(0);

    // 4. LDS -> A fragments (swizzled), cvt if f32
    const char* bb = smem + (ti&1)*TILEB;
    s16x8 afr[2][4];
    #pragma unroll
    for (int kh = 0; kh < 2; ++kh){
      #pragma unroll
      for (int i = 0; i < 4; ++i){
        int row_l = wr*64 + i*16 + m15;
        if (ABF){
          int s = kh*4 + kg;
          int sw = s ^ (row_l & SMSK);
          afr[kh][i] = *(const s16x8*)(bb + row_l*ROWB + sw*16);
        } else {
          int s0 = kh*8 + kg*2;
          int sw0 = s0 ^ (row_l & SMSK);
          int sw1 = (s0+1) ^ (row_l & SMSK);
          float4 lo = *(const float4*)(bb + row_l*ROWB + sw0*16);
          float4 hi = *(const float4*)(bb + row_l*ROWB + sw1*16);
          s16x8 v;
          v[0]=(short)f2b(lo.x); v[1]=(short)f2b(lo.y); v[2]=(short)f2b(lo.z); v[3]=(short)f2b(lo.w);
          v[4]=(short)f2b(hi.x); v[5]=(short)f2b(hi.y); v[6]=(short)f2b(hi.z); v[7]=(short)f2b(hi.w);
          afr[kh][i] = v;
        }
      }
    }

    // 5. MFMA (compiler inserts lgkmcnt for afr + vmcnt(IW) for bfr)
    #pragma unroll
    for (int kh = 0; kh < 2; ++kh)
      #pragma unroll
      for (int i = 0; i < 4; ++i)
        #pragma unroll
        for (int j = 0; j < 4; ++j)
          acc[i][j] = __builtin_amdgcn_mfma_f32_16x16x32_bf16(afr[kh][i], bfr[kh][j], acc[i][j], 0, 0, 0);

    // 6. read-protect: nobody overwrites buf(ti) (via stage(ti+2)) until all read it
    __builtin_amdgcn_sched_barrier(0);
    __builtin_amdgcn_s_barrier();
  }

  __syncthreads();   // full drain before LDS reuse in epilogue

  if (OBF){
    // repack epilogue: acc -> LDS u16 [128][136] -> coalesced 16B stores
    u16* cs = (u16*)smem;
    #pragma unroll
    for (int j = 0; j < 4; ++j){
      int colg = c0 + wc*64 + j*16 + m15;
      float bv = bias[colg];
      #pragma unroll
      for (int i = 0; i < 4; ++i){
        int rl = wr*64 + i*16 + kg*4;
        #pragma unroll
        for (int q = 0; q < 4; ++q){
          float v = acc[i][j][q] + bv;
          if (RELU) v = fmaxf(v, 0.f);
          cs[(rl+q)*136 + wc*64 + j*16 + m15] = f2b(v);
        }
      }
    }
    __syncthreads();
    int rr = t >> 1, hh = t & 1;
    int go = r0 + rr;
    if (go < M){
      u16* dst = (u16*)Cv + (size_t)go*N + c0 + hh*64;
      const u16* sp = &cs[rr*136 + hh*64];
      #pragma unroll
      for (int c = 0; c < 8; ++c) *(s16x8*)(dst + c*8) = *(const s16x8*)(sp + c*8);
    }
  } else {
    #pragma unroll
    for (int j = 0; j < 4; ++j){
      int colg = c0 + wc*64 + j*16 + m15;
      float bv = bias[colg];
      #pragma unroll
      for (int i = 0; i < 4; ++i){
        int rbase = r0 + wr*64 + i*16 + kg*4;
        #pragma unroll
        for (int q = 0; q < 4; ++q){
          int row = rbase + q;
          if (row < M){
            float v = acc[i][j][q] + bv;
            if (RELU) v = fmaxf(v, 0.f);
            ((float*)Cv)[(size_t)row*N + colg] = v;
          }
        }
      }
    }
  }
}

// ---- CSR pull aggregation, 4x-unrolled edge loop for memory-level parallelism ----
__global__ __launch_bounds__(256) void agg_kernel(const u16* __restrict__ X,
    const int* __restrict__ off, const int* __restrict__ lst,
    const float* __restrict__ so, const float* __restrict__ ri,
    u16* __restrict__ out, int nd)
{
  int lane = threadIdx.x & 63, wv = threadIdx.x >> 6;
  int d = blockIdx.x*4 + wv;
  if (d >= nd) return;
  int e0 = off[d], e1 = off[d+1];
  float a0=0.f, a1=0.f, a2=0.f, a3=0.f;
  int e = e0;
  for (; e + 4 <= e1; e += 4){
    int s0 = lst[e], s1 = lst[e+1], s2 = lst[e+2], s3 = lst[e+3];
    float c0 = so[s0], c1 = so[s1], c2 = so[s2], c3 = so[s3];
    ushort4 u0 = ((const ushort4*)X)[(size_t)s0*64 + lane];
    ushort4 u1 = ((const ushort4*)X)[(size_t)s1*64 + lane];
    ushort4 u2 = ((const ushort4*)X)[(size_t)s2*64 + lane];
    ushort4 u3 = ((const ushort4*)X)[(size_t)s3*64 + lane];
    a0 = fmaf(b2f(u0.x), c0, a0); a1 = fmaf(b2f(u0.y), c0, a1);
    a2 = fmaf(b2f(u0.z), c0, a2); a3 = fmaf(b2f(u0.w), c0, a3);
    a0 = fmaf(b2f(u1.x), c1, a0); a1 = fmaf(b2f(u1.y), c1, a1);
    a2 = fmaf(b2f(u1.z), c1, a2); a3 = fmaf(b2f(u1.w), c1, a3);
    a0 = fmaf(b2f(u2.x), c2, a0); a1 = fmaf(b2f(u2.y), c2, a1);
    a2 = fmaf(b2f(u2.z), c2, a2); a3 = fmaf(b2f(u2.w), c2, a3);
    a0 = fmaf(b2f(u3.x), c3, a0); a1 = fmaf(b2f(u3.y), c3, a1);
    a2 = fmaf(b2f(u3.z), c3, a2); a3 = fmaf(b2f(u3.w), c3, a3);
  }
  for (; e < e1; ++e){
    int s = lst[e];
    float sc = so[s];
    ushort4 u = ((const ushort4*)X)[(size_t)s*64 + lane];
    a0 = fmaf(b2f(u.x), sc, a0);
    a1 = fmaf(b2f(u.y), sc, a1);
    a2 = fmaf(b2f(u.z), sc, a2);
    a3 = fmaf(b2f(u.w), sc, a3);
  }
  float r = ri[d];
  ushort4 o;
  o.x = f2b(a0*r); o.y = f2b(a1*r); o.z = f2b(a2*r); o.w = f2b(a3*r);
  ((ushort4*)out)[(size_t)d*64 + lane] = o;
}

// ---- LayerNorm over 256 cols, in-place bf16, one wave per row ----
__global__ __launch_bounds__(256) void ln_kernel(u16* __restrict__ H,
    const float* __restrict__ g, const float* __restrict__ b, int n)
{
  int lane = threadIdx.x & 63, wv = threadIdx.x >> 6;
  int r = blockIdx.x*4 + wv;
  if (r >= n) return;
  ushort4 u = ((const ushort4*)H)[(size_t)r*64 + lane];
  float x0=b2f(u.x), x1=b2f(u.y), x2=b2f(u.z), x3=b2f(u.w);
  float s = x0+x1+x2+x3;
  #pragma unroll
  for (int d=1; d<64; d<<=1) s += __shfl_xor(s, d);
  float mu = s * (1.f/256.f);
  float d0=x0-mu, d1=x1-mu, d2=x2-mu, d3=x3-mu;
  float v = d0*d0 + d1*d1 + d2*d2 + d3*d3;
  #pragma unroll
  for (int d=1; d<64; d<<=1) v += __shfl_xor(v, d);
  float inv = rsqrtf(v*(1.f/256.f) + 1e-5f);
  float4 gv = ((const float4*)g)[lane];
  float4 bv = ((const float4*)b)[lane];
  ushort4 o;
  o.x = f2b(d0*inv*gv.x + bv.x);
  o.y = f2b(d1*inv*gv.y + bv.y);
  o.z = f2b(d2*inv*gv.z + bv.z);
  o.w = f2b(d3*inv*gv.w + bv.w);
  ((ushort4*)H)[(size_t)r*64 + lane] = o;
}

// ---- row L2-normalize, 128 cols, one wave per row ----
__global__ __launch_bounds__(256) void rownorm_kernel(const float* __restrict__ T,
    float* __restrict__ out, int n)
{
  int lane = threadIdx.x & 63, wv = threadIdx.x >> 6;
  int r = blockIdx.x*4 + wv;
  if (r >= n) return;
  float2 x = ((const float2*)T)[(size_t)r*64 + lane];
  float s = x.x*x.x + x.y*x.y;
  #pragma unroll
  for (int d=1; d<64; d<<=1) s += __shfl_xor(s, d);
  float nrm = sqrtf(s);
  float sc = 1.f / fmaxf(nrm, 1e-12f);
  float2 o; o.x = x.x*sc; o.y = x.y*sc;
  ((float2*)out)[(size_t)r*64 + lane] = o;
}

extern "C" void kernel_launch(void* const* d_in, const int* in_sizes, int n_in,
                              void* d_out, int out_size, void* d_ws, size_t ws_size,
                              hipStream_t stream)
{
  const float* feats = (const float*)d_in[0];
  const int*   b0s   = (const int*)d_in[1];
  const int*   b0d   = (const int*)d_in[2];
  const int*   b1s   = (const int*)d_in[3];
  const int*   b1d   = (const int*)d_in[4];
  const float* W1    = (const float*)d_in[5];
  const float* bias1 = (const float*)d_in[6];
  const float* Wc    = (const float*)d_in[7];
  const float* bc    = (const float*)d_in[8];
  const float* lng   = (const float*)d_in[9];
  const float* lnb   = (const float*)d_in[10];
  const float* Wo    = (const float*)d_in[11];
  const float* bo    = (const float*)d_in[12];
  const int E0 = in_sizes[1];
  const int E1 = in_sizes[3];
  (void)n_in; (void)out_size; (void)ws_size;

  char* p = (char*)d_ws;
  auto alloc = [&](size_t bytes)->void*{ void* q = (void*)p; p += (bytes + 255) & ~(size_t)255; return q; };
  u16*   g1   = (u16*)  alloc((size_t)NN0*HD*2);     // GEMM1 out; reused for conv1 out + LN
  u16*   hb   = (u16*)  alloc((size_t)NN1*HD*2);     // agg1 out
  u16*   ag2  = (u16*)  alloc((size_t)NN2*HD*2);
  float* c2   = (float*)alloc((size_t)NN2*OUT_D*4);
  u16*   W1P  = (u16*)  alloc((size_t)HD*IN_DIM*2);
  u16*   WcP  = (u16*)  alloc((size_t)HD*HD*2);
  u16*   WoP  = (u16*)  alloc((size_t)OUT_D*HD*2);
  char* cnt_begin = p;
  int* outc0 = (int*)alloc((size_t)NN0*4);
  int* inc0  = (int*)alloc((size_t)NN1*4);
  int* outc1 = (int*)alloc((size_t)NN1*4);
  int* inc1  = (int*)alloc((size_t)NN2*4);
  char* cnt_end = p;
  float* so0 = (float*)alloc((size_t)NN0*4);
  float* ri0 = (float*)alloc((size_t)NN1*4);
  float* so1 = (float*)alloc((size_t)NN1*4);
  float* ri1 = (float*)alloc((size_t)NN2*4);
  int* off0  = (int*)alloc((size_t)(NN1+1)*4);
  int* cur0  = (int*)alloc((size_t)NN1*4);
  int* off1  = (int*)alloc((size_t)(NN2+1)*4);
  int* cur1  = (int*)alloc((size_t)NN2*4);
  int* lst0  = (int*)alloc((size_t)800000*4);
  int* lst1  = (int*)alloc((size_t)160000*4);

  hipMemsetAsync(cnt_begin, 0, (size_t)(cnt_end - cnt_begin), stream);

  // graph prep (fused: 5 launches)
  {
    int Emax = E0 > E1 ? E0 : E1;
    prep_deg<<<(Emax+255)/256, 256, 0, stream>>>(b0s, b0d, E0, b1s, b1d, E1,
                                                 outc0, inc0, outc1, inc1);
    prep_scale<<<(NN0+255)/256, 256, 0, stream>>>(outc0, so0, inc0, ri0, outc1, so1, inc1, ri1);
    scan2_kernel<<<2, 1024, 0, stream>>>(inc0, off0, cur0, NN1, inc1, off1, cur1, NN2);
    fill2_kernel<<<(Emax+255)/256, 256, 0, stream>>>(b0s, b0d, E0, cur0, lst0,
                                                     b1s, b1d, E1, cur1, lst1);
    wpack3<<<112, 256, 0, stream>>>(W1, W1P, Wc, WcP, Wo, WoP);
  }

  // h = feats @ W1 + bias1   [200000,512]@[512,256] -> g1 (bf16)
  {
    int nblk = ((NN0+127)/128) * (HD/128);
    gemm_glds<IN_DIM, HD, false, false, true><<<nblk, 256, 0, stream>>>(feats, W1P, bias1, g1, NN0);
  }
  // agg1 over b0 -> hb
  agg_kernel<<<(NN1+3)/4, 256, 0, stream>>>(g1, off0, lst0, so0, ri0, hb, NN1);
  // conv1 = relu(agg1 @ Wc + bc)  [50000,256]@[256,256] -> g1 (region reuse; hb intact)
  {
    int nblk = ((NN1+127)/128) * (HD/128);
    gemm_glds<HD, HD, true, true, true><<<nblk, 256, 0, stream>>>(hb, WcP, bc, g1, NN1);
  }
  // LayerNorm in-place on g1[0:NN1]
  ln_kernel<<<(NN1+3)/4, 256, 0, stream>>>(g1, lng, lnb, NN1);
  // agg2 over b1 -> ag2
  agg_kernel<<<(NN2+3)/4, 256, 0, stream>>>(g1, off1, lst1, so1, ri1, ag2, NN2);
  // conv2 = agg2 @ Wo + bo  [10000,256]@[256,128] -> c2 (f32)
  {
    int nblk = ((NN2+127)/128) * (OUT_D/128);
    gemm_glds<HD, OUT_D, true, false, false><<<nblk, 256, 0, stream>>>(ag2, WoP, bo, c2, NN2);
  }
  // row L2 normalize -> d_out (f32)
  rownorm_kernel<<<(NN2+3)/4, 256, 0, stream>>>(c2, (float*)d_out, NN2);
}